// Round 8
// baseline (297.340 us; speedup 1.0000x reference)
//
#include <hip/hip_runtime.h>
#include <hip/hip_bf16.h>
#include <stdint.h>

typedef unsigned short ushort_t;
typedef __attribute__((ext_vector_type(8))) short short8;
typedef __attribute__((ext_vector_type(4))) float f32x4;

__device__ __forceinline__ float b2f(ushort_t u) {
    union { uint32_t i; float f; } v; v.i = ((uint32_t)u) << 16; return v.f;
}
__device__ __forceinline__ ushort_t f2b(float f) {
    union { float f; uint32_t i; } v; v.f = f;
    uint32_t r = v.i + 0x7fff + ((v.i >> 16) & 1);
    return (ushort_t)(r >> 16);
}

#if __has_builtin(__builtin_amdgcn_exp2f)
#define EXP2(x) __builtin_amdgcn_exp2f(x)
#else
#define EXP2(x) __expf((x) * 0.69314718056f)
#endif

// async global->LDS, 16B per lane; lds base must be wave-uniform
__device__ __forceinline__ void ll16(const ushort_t* g, ushort_t* l) {
    __builtin_amdgcn_global_load_lds(
        (const __attribute__((address_space(1))) uint32_t*)g,
        (__attribute__((address_space(3))) uint32_t*)l, 16, 0, 0);
}

// DPP cross-lane add (VALU pipe)
template <int CTRL>
__device__ __forceinline__ float dpp_add(float p) {
    int v = __builtin_amdgcn_update_dpp(0, __float_as_int(p), CTRL, 0xF, 0xF, true);
    return p + __int_as_float(v);
}
#define DPP_XOR1 0xB1
#define DPP_XOR2 0x4E
#define DPP_HMIR 0x141

// ---------------------------------------------------------------------------
// Coalesced epilogues: wave's 16x64 output group via private LDS scratch.
// ---------------------------------------------------------------------------
__device__ __forceinline__ void epi_wave_f32(
    float* sw, const f32x4* accg, float* dst0, int ldc, int lane)
{
    const int quad = lane >> 4, lr = lane & 15;
#pragma unroll
    for (int j = 0; j < 4; j++)
#pragma unroll
        for (int r = 0; r < 4; r++)
            sw[(quad * 4 + r) * 64 + j * 16 + lr] = accg[j][r];
    __asm__ volatile("s_waitcnt lgkmcnt(0)" ::: "memory");
#pragma unroll
    for (int t = 0; t < 4; t++) {
        int row = t * 4 + quad;
        float4 v = *(const float4*)(&sw[row * 64 + lr * 4]);
        *(float4*)(dst0 + (size_t)row * ldc + lr * 4) = v;
    }
}

__device__ __forceinline__ void epi_wave_b16(
    float* sw, const f32x4* accg, ushort_t* dst0, int ldc, int lane)
{
    const int quad = lane >> 4, lr = lane & 15;
#pragma unroll
    for (int j = 0; j < 4; j++)
#pragma unroll
        for (int r = 0; r < 4; r++)
            sw[(quad * 4 + r) * 64 + j * 16 + lr] = accg[j][r];
    __asm__ volatile("s_waitcnt lgkmcnt(0)" ::: "memory");
#pragma unroll
    for (int t = 0; t < 4; t++) {
        int row = t * 4 + quad;
        float4 v = *(const float4*)(&sw[row * 64 + lr * 4]);
        ushort4 o; o.x = f2b(v.x); o.y = f2b(v.y); o.z = f2b(v.z); o.w = f2b(v.w);
        *(ushort4*)(dst0 + (size_t)row * ldc + lr * 4) = o;
    }
}

// ---------------------------------------------------------------------------
// Fused multi-tensor fp32 -> bf16 cast (7 segments, 1 launch)
// ---------------------------------------------------------------------------
struct CastSeg { const float4* src; ushort4* dst; };
struct CastArgs { CastSeg seg[7]; int start[8]; };

__global__ __launch_bounds__(256) void cast_multi(CastArgs a)
{
    int g = blockIdx.x * 256 + threadIdx.x;
    if (g >= a.start[7]) return;
    int s = 0;
#pragma unroll
    for (int i = 1; i < 7; i++) s += (g >= a.start[i]);
    int i = g - a.start[s];
    float4 v = a.seg[s].src[i];
    ushort4 o;
    o.x = f2b(v.x); o.y = f2b(v.y); o.z = f2b(v.z); o.w = f2b(v.w);
    a.seg[s].dst[i] = o;
}

#define BK 32

// ---------------------------------------------------------------------------
// G1: xz16 = x @ W_in^T (2048 x 4096, K=1024), bf16 out, coalesced epilogue.
// ---------------------------------------------------------------------------
__global__ __launch_bounds__(256) void gemm_g1(
    const ushort_t* __restrict__ A, int lda,
    const ushort_t* __restrict__ B, int ldb,
    ushort_t* __restrict__ Cout, int ldc, int Kd)
{
    __shared__ ushort_t As[128 * BK];
    __shared__ ushort_t Bs[128 * BK];
    __shared__ float sepi[4][1024];

    const int tid  = threadIdx.x;
    const int m0   = blockIdx.y * 128;
    const int n0   = blockIdx.x * 128;
    const int wv   = tid >> 6;
    const int lane = tid & 63;
    const int wm   = (wv >> 1) * 64;
    const int wn   = (wv & 1) * 64;
    const int lr   = lane & 15;
    const int quad = lane >> 4;

    f32x4 acc[4][4];
#pragma unroll
    for (int i = 0; i < 4; i++)
#pragma unroll
        for (int j = 0; j < 4; j++) acc[i][j] = f32x4{0.f, 0.f, 0.f, 0.f};

    const int srA = wv * 32 + (lane >> 2);
    const int scA = (lane & 3) * 8;

    for (int k0 = 0; k0 < Kd; k0 += BK) {
        ll16(A + (size_t)(m0 + srA) * lda + k0 + scA,      &As[wv * 1024]);
        ll16(A + (size_t)(m0 + srA + 16) * lda + k0 + scA, &As[wv * 1024 + 512]);
        ll16(B + (size_t)(n0 + srA) * ldb + k0 + scA,      &Bs[wv * 1024]);
        ll16(B + (size_t)(n0 + srA + 16) * ldb + k0 + scA, &Bs[wv * 1024 + 512]);
        __syncthreads();

        short8 af[4], bf[4];
#pragma unroll
        for (int i = 0; i < 4; i++)
            af[i] = *(const short8*)(&As[(wm + i * 16 + lr) * BK + quad * 8]);
#pragma unroll
        for (int j = 0; j < 4; j++)
            bf[j] = *(const short8*)(&Bs[(wn + j * 16 + lr) * BK + quad * 8]);
#pragma unroll
        for (int i = 0; i < 4; i++)
#pragma unroll
            for (int j = 0; j < 4; j++)
                acc[i][j] = __builtin_amdgcn_mfma_f32_16x16x32_bf16(af[i], bf[j], acc[i][j], 0, 0, 0);
        __syncthreads();
    }

#pragma unroll
    for (int g = 0; g < 4; g++)
        epi_wave_b16(sepi[wv], acc[g],
                     Cout + (size_t)(m0 + wm + g * 16) * ldc + n0 + wn, ldc, lane);
}

// ---------------------------------------------------------------------------
// G4: out = 0.5*(yf + yb) @ W_out^T (2048 x 1024, K=2048), fused combine in
// A-staging (register path), fp32 out, BM=64.
// ---------------------------------------------------------------------------
__global__ __launch_bounds__(256) void gemm_g4(
    const ushort_t* __restrict__ Ayf, const ushort_t* __restrict__ Ayb,
    const ushort_t* __restrict__ B, int ldb,
    float* __restrict__ Cout, int ldc, int Kd)
{
    __shared__ ushort_t As[64 * BK];
    __shared__ ushort_t Bs[128 * BK];
    __shared__ float sepi[4][1024];

    const int tid  = threadIdx.x;
    const int m0   = blockIdx.y * 64;
    const int n0   = blockIdx.x * 128;
    const int wv   = tid >> 6;
    const int lane = tid & 63;
    const int wm   = (wv >> 1) * 32;
    const int wn   = (wv & 1) * 64;
    const int lr   = lane & 15;
    const int quad = lane >> 4;

    f32x4 acc[2][4];
#pragma unroll
    for (int i = 0; i < 2; i++)
#pragma unroll
        for (int j = 0; j < 4; j++) acc[i][j] = f32x4{0.f, 0.f, 0.f, 0.f};

    const int srA = wv * 16 + (lane >> 2);
    const int srB = wv * 32 + (lane >> 2);
    const int sc  = (lane & 3) * 8;

    for (int k0 = 0; k0 < Kd; k0 += BK) {
        // A fused: a = 0.5*(yf + yb), both original-time-indexed
        {
            size_t aoff = (size_t)(m0 + srA) * 2048 + k0 + sc;
            uint4 uf = *(const uint4*)(Ayf + aoff);
            uint4 ub = *(const uint4*)(Ayb + aoff);
            const uint32_t fw[4] = { uf.x, uf.y, uf.z, uf.w };
            const uint32_t bw[4] = { ub.x, ub.y, ub.z, ub.w };
            uint32_t ow[4];
#pragma unroll
            for (int k = 0; k < 4; k++) {
                float a0 = 0.5f * (b2f((ushort_t)(fw[k] & 0xffff)) + b2f((ushort_t)(bw[k] & 0xffff)));
                float a1 = 0.5f * (b2f((ushort_t)(fw[k] >> 16))    + b2f((ushort_t)(bw[k] >> 16)));
                ow[k] = (uint32_t)f2b(a0) | ((uint32_t)f2b(a1) << 16);
            }
            *(uint4*)(&As[srA * BK + sc]) = make_uint4(ow[0], ow[1], ow[2], ow[3]);
        }
        ll16(B + (size_t)(n0 + srB) * ldb + k0 + sc,      &Bs[wv * 1024]);
        ll16(B + (size_t)(n0 + srB + 16) * ldb + k0 + sc, &Bs[wv * 1024 + 512]);
        __syncthreads();

        short8 af[2], bf[4];
#pragma unroll
        for (int i = 0; i < 2; i++)
            af[i] = *(const short8*)(&As[(wm + i * 16 + lr) * BK + quad * 8]);
#pragma unroll
        for (int j = 0; j < 4; j++)
            bf[j] = *(const short8*)(&Bs[(wn + j * 16 + lr) * BK + quad * 8]);
#pragma unroll
        for (int i = 0; i < 2; i++)
#pragma unroll
            for (int j = 0; j < 4; j++)
                acc[i][j] = __builtin_amdgcn_mfma_f32_16x16x32_bf16(af[i], bf[j], acc[i][j], 0, 0, 0);
        __syncthreads();
    }

#pragma unroll
    for (int g = 0; g < 2; g++)
        epi_wave_f32(sepi[wv], acc[g],
                     Cout + (size_t)(m0 + wm + g * 16) * ldc + n0 + wn, ldc, lane);
}

// ---------------------------------------------------------------------------
// G2: dbc partials. grid (SK=8, M/128=16, br=2). N=96, guarded coalesced epi.
// ---------------------------------------------------------------------------
__global__ __launch_bounds__(256) void gemm_g2(
    const ushort_t* __restrict__ xc, const ushort_t* __restrict__ wx,
    float* __restrict__ part)
{
    __shared__ ushort_t As[128 * BK];
    __shared__ ushort_t Bs[128 * BK];
    __shared__ float sepi[4][1024];

    const int sk = blockIdx.x, mb = blockIdx.y, br = blockIdx.z;
    const ushort_t* A = xc + (size_t)br * 2048 * 2048;
    const ushort_t* B = wx + (size_t)br * 96 * 2048;
    float* C = part + (size_t)(sk * 2 + br) * 2048 * 96;
    const int m0 = mb * 128;
    const int kb = sk * 256;

    const int tid  = threadIdx.x;
    const int wv   = tid >> 6;
    const int lane = tid & 63;
    const int wm   = (wv >> 1) * 64;
    const int wn   = (wv & 1) * 64;
    const int lr   = lane & 15;
    const int quad = lane >> 4;

    f32x4 acc[4][4];
#pragma unroll
    for (int i = 0; i < 4; i++)
#pragma unroll
        for (int j = 0; j < 4; j++) acc[i][j] = f32x4{0.f, 0.f, 0.f, 0.f};

    const int srA = wv * 32 + (lane >> 2);
    const int sc  = (lane & 3) * 8;

    for (int k0 = kb; k0 < kb + 256; k0 += BK) {
        ll16(A + (size_t)(m0 + srA) * 2048 + k0 + sc,      &As[wv * 1024]);
        ll16(A + (size_t)(m0 + srA + 16) * 2048 + k0 + sc, &As[wv * 1024 + 512]);
        ll16(B + (size_t)(srA) * 2048 + k0 + sc,           &Bs[wv * 1024]);
        ll16(B + (size_t)(srA + 16) * 2048 + k0 + sc,      &Bs[wv * 1024 + 512]);
        __syncthreads();

        short8 af[4], bf[4];
#pragma unroll
        for (int i = 0; i < 4; i++)
            af[i] = *(const short8*)(&As[(wm + i * 16 + lr) * BK + quad * 8]);
#pragma unroll
        for (int j = 0; j < 4; j++)
            bf[j] = *(const short8*)(&Bs[(wn + j * 16 + lr) * BK + quad * 8]);
#pragma unroll
        for (int i = 0; i < 4; i++)
#pragma unroll
            for (int j = 0; j < 4; j++)
                acc[i][j] = __builtin_amdgcn_mfma_f32_16x16x32_bf16(af[i], bf[j], acc[i][j], 0, 0, 0);
        __syncthreads();
    }

    float* sw = sepi[wv];
#pragma unroll
    for (int g = 0; g < 4; g++) {
#pragma unroll
        for (int j = 0; j < 4; j++)
#pragma unroll
            for (int r = 0; r < 4; r++)
                sw[(quad * 4 + r) * 64 + j * 16 + lr] = acc[g][j][r];
        __asm__ volatile("s_waitcnt lgkmcnt(0)" ::: "memory");
        int col = wn + lr * 4;
#pragma unroll
        for (int t = 0; t < 4; t++) {
            int row = t * 4 + quad;
            if (col < 96) {
                float4 v = *(const float4*)(&sw[row * 64 + lr * 4]);
                *(float4*)(C + (size_t)(m0 + wm + g * 16 + row) * 96 + col) = v;
            }
        }
    }
}

__global__ __launch_bounds__(256) void reduce_dbc(
    const float4* __restrict__ part, ushort4* __restrict__ dbc16)
{
    int g = blockIdx.x * 256 + threadIdx.x;   // 98304 total
    const int S = 2 * 2048 * 96 / 4;
    float4 r = part[g];
#pragma unroll
    for (int i = 1; i < 8; i++) {
        float4 p = part[g + i * S];
        r.x += p.x; r.y += p.y; r.z += p.z; r.w += p.w;
    }
    ushort4 o; o.x = f2b(r.x); o.y = f2b(r.y); o.z = f2b(r.z); o.w = f2b(r.w);
    dbc16[g] = o;
}

// ---------------------------------------------------------------------------
// G3: delta16 = softplus(dbc[:, :64] @ Wdt^T + b_dt), bf16 out, fast softplus.
// ---------------------------------------------------------------------------
__global__ __launch_bounds__(256) void gemm_g3(
    const ushort_t* __restrict__ dbc16, const ushort_t* __restrict__ wdt,
    ushort_t* __restrict__ delta,
    const float* __restrict__ bdt_f, const float* __restrict__ bdt_b)
{
    __shared__ ushort_t As[128 * BK];
    __shared__ ushort_t Bs[128 * BK];
    __shared__ float sepi[4][1024];

    const int br = blockIdx.z;
    const ushort_t* A = dbc16 + (size_t)br * 2048 * 96;
    const ushort_t* B = wdt + (size_t)br * 2048 * 64;
    ushort_t* C = delta + (size_t)br * 2048 * 2048;
    const float* bias = br ? bdt_b : bdt_f;

    const int tid  = threadIdx.x;
    const int m0   = blockIdx.y * 128;
    const int n0   = blockIdx.x * 128;
    const int wv   = tid >> 6;
    const int lane = tid & 63;
    const int wm   = (wv >> 1) * 64;
    const int wn   = (wv & 1) * 64;
    const int lr   = lane & 15;
    const int quad = lane >> 4;

    f32x4 acc[4][4];
#pragma unroll
    for (int i = 0; i < 4; i++)
#pragma unroll
        for (int j = 0; j < 4; j++) acc[i][j] = f32x4{0.f, 0.f, 0.f, 0.f};

    const int srA = wv * 32 + (lane >> 2);
    const int sc  = (lane & 3) * 8;

    for (int k0 = 0; k0 < 64; k0 += BK) {
        ll16(A + (size_t)(m0 + srA) * 96 + k0 + sc,       &As[wv * 1024]);
        ll16(A + (size_t)(m0 + srA + 16) * 96 + k0 + sc,  &As[wv * 1024 + 512]);
        ll16(B + (size_t)(n0 + srA) * 64 + k0 + sc,       &Bs[wv * 1024]);
        ll16(B + (size_t)(n0 + srA + 16) * 64 + k0 + sc,  &Bs[wv * 1024 + 512]);
        __syncthreads();

        short8 af[4], bf[4];
#pragma unroll
        for (int i = 0; i < 4; i++)
            af[i] = *(const short8*)(&As[(wm + i * 16 + lr) * BK + quad * 8]);
#pragma unroll
        for (int j = 0; j < 4; j++)
            bf[j] = *(const short8*)(&Bs[(wn + j * 16 + lr) * BK + quad * 8]);
#pragma unroll
        for (int i = 0; i < 4; i++)
#pragma unroll
            for (int j = 0; j < 4; j++)
                acc[i][j] = __builtin_amdgcn_mfma_f32_16x16x32_bf16(af[i], bf[j], acc[i][j], 0, 0, 0);
        __syncthreads();
    }

    float bn[4];
#pragma unroll
    for (int j = 0; j < 4; j++) bn[j] = bias[n0 + wn + j * 16 + lr];
#pragma unroll
    for (int g = 0; g < 4; g++)
#pragma unroll
        for (int j = 0; j < 4; j++)
#pragma unroll
            for (int r = 0; r < 4; r++) {
                float x = acc[g][j][r] + bn[j];
                float sp = fmaxf(x, 0.f) + __logf(1.f + __expf(-fabsf(x)));
                acc[g][j][r] = sp;
            }

#pragma unroll
    for (int g = 0; g < 4; g++)
        epi_wave_b16(sepi[wv], acc[g],
                     C + (size_t)(m0 + wm + g * 16) * 2048 + n0 + wn, 2048, lane);
}

// ---------------------------------------------------------------------------
// Causal depthwise conv (K=4) + bias + silu, vectorized: thread = 8 e's.
// ---------------------------------------------------------------------------
__global__ __launch_bounds__(256) void conv_silu_kernel(
    const ushort_t* __restrict__ xz,
    const float* __restrict__ w_f, const float* __restrict__ cb_f,
    const float* __restrict__ w_b, const float* __restrict__ cb_b,
    ushort_t* __restrict__ xc16)
{
    int g = blockIdx.x * 256 + threadIdx.x;   // 1048576 total
    int e8 = g & 255;
    int t  = (g >> 8) & 511;
    int b  = (g >> 17) & 3;
    int br = g >> 19;
    int e  = e8 * 8;

    const float* w  = br ? w_b  : w_f;
    const float* cb = br ? cb_b : cb_f;

    float acc[8];
#pragma unroll
    for (int j = 0; j < 8; j++) acc[j] = cb[e + j];
    float4 wv[8];
#pragma unroll
    for (int j = 0; j < 8; j++) wv[j] = *(const float4*)(w + (e + j) * 4);

#pragma unroll
    for (int k = 0; k < 4; k++) {
        int tp = t - 3 + k;
        if (tp >= 0) {
            int row = br ? (511 - tp) : tp;
            uint4 u = *(const uint4*)(xz + ((size_t)(b * 512 + row)) * 4096 + e);
            const uint32_t uw[4] = { u.x, u.y, u.z, u.w };
#pragma unroll
            for (int q = 0; q < 4; q++) {
                float v0 = b2f((ushort_t)(uw[q] & 0xffff));
                float v1 = b2f((ushort_t)(uw[q] >> 16));
                const float* wq0 = (const float*)&wv[2 * q];
                const float* wq1 = (const float*)&wv[2 * q + 1];
                acc[2 * q]     += wq0[k] * v0;
                acc[2 * q + 1] += wq1[k] * v1;
            }
        }
    }
    uint32_t ow[4];
#pragma unroll
    for (int q = 0; q < 4; q++) {
        float s0 = acc[2 * q]     / (1.f + __expf(-acc[2 * q]));
        float s1 = acc[2 * q + 1] / (1.f + __expf(-acc[2 * q + 1]));
        ow[q] = (uint32_t)f2b(s0) | ((uint32_t)f2b(s1) << 16);
    }
    *(uint4*)(xc16 + ((size_t)(br * 4 + b) * 512 + t) * 2048 + e) =
        make_uint4(ow[0], ow[1], ow[2], ow[3]);
}

// ---------------------------------------------------------------------------
// Selective scan v8: as v7 but y stored at ORIGINAL-time rows for both
// branches (so G4 can fuse the combine without reversal indexing).
// ---------------------------------------------------------------------------
__global__ __launch_bounds__(256) void scan_kernel(
    const ushort_t* __restrict__ delta,   // [2][B][L][ED] bf16
    const ushort_t* __restrict__ xc,      // [2][B][L][ED] bf16
    const ushort_t* __restrict__ dbc16,   // [2][B][L][96] bf16
    const ushort_t* __restrict__ xz,      // [B][L][4096] bf16 (z half)
    const float* __restrict__ Alog_f, const float* __restrict__ Alog_b,
    const float* __restrict__ Dp_f,   const float* __restrict__ Dp_b,
    ushort_t* __restrict__ yf, ushort_t* __restrict__ yb)
{
    const int blk = blockIdx.x;            // 0..511
    const int eg = blk & 63;
    const int b  = (blk >> 6) & 3;
    const int br = blk >> 8;
    const int e0 = eg * 32;

    const int tid = threadIdx.x;
    const int n2  = tid & 7;
    const int el  = tid >> 3;              // 0..31
    const int e   = e0 + el;

    const float* Alog = br ? Alog_b : Alog_f;
    const float* Dpp  = br ? Dp_b   : Dp_f;
    const float A0 = -__expf(Alog[e * 16 + n2]) * 1.44269504f;
    const float A1 = -__expf(Alog[e * 16 + n2 + 8]) * 1.44269504f;

    size_t tb = ((size_t)br * 4 + b) * 512;
    const ushort_t* dlt  = delta + tb * 2048;
    const ushort_t* xcb  = xc    + tb * 2048;
    const ushort_t* dbcb = dbc16 + tb * 96;
    ushort_t* y = (br ? yb : yf) + (size_t)b * 512 * 2048;

    __shared__ float    sd[2][32][68];     // d[e][t^swz]
    __shared__ ushort_t sx[2][32][72];     // x[e][t^swz]
    __shared__ float    sB[2][16][68];     // B[n][t^swz] fp32
    __shared__ float    sC[2][16][68];     // C[n][t^swz] fp32
    __shared__ float    sy[2][64][36];     // y[t][e], ping-pong

    const int stt = tid >> 2;              // 0..63 (t within chunk)
    const int seg = tid & 3;               // 8-elem column group
    const int swz = seg * 8;
    const int scol = stt ^ swz;

    float4 rD0 = *(const float4*)(Dpp + e0 + seg * 8);
    float4 rD1 = *(const float4*)(Dpp + e0 + seg * 8 + 4);

    uint4 rdx, rx, rbc, rz;
    uint4 rx_c, rx_f, rz_c, rz_f;

    auto load_regs = [&](int c) {
        int t0 = c * 64;
        rdx = *(const uint4*)(dlt + (size_t)(t0 + stt) * 2048 + e0 + seg * 8);
        rx  = *(const uint4*)(xcb + (size_t)(t0 + stt) * 2048 + e0 + seg * 8);
        rbc = *(const uint4*)(dbcb + (size_t)(t0 + stt) * 96 + 64 + seg * 8);
        int orow = br ? (511 - (t0 + stt)) : (t0 + stt);
        rz  = *(const uint4*)(xz + ((size_t)(b * 512 + orow)) * 4096 + 2048 + e0 + seg * 8);
    };
    auto write_lds = [&](int buf) {
        const uint32_t dw[4] = { rdx.x, rdx.y, rdx.z, rdx.w };
#pragma unroll
        for (int k = 0; k < 4; k++) {
            sd[buf][seg * 8 + 2 * k][scol]     = b2f((ushort_t)(dw[k] & 0xffff));
            sd[buf][seg * 8 + 2 * k + 1][scol] = b2f((ushort_t)(dw[k] >> 16));
        }
        const uint32_t xw[4] = { rx.x, rx.y, rx.z, rx.w };
#pragma unroll
        for (int k = 0; k < 4; k++) {
            sx[buf][seg * 8 + 2 * k][scol]     = (ushort_t)(xw[k] & 0xffff);
            sx[buf][seg * 8 + 2 * k + 1][scol] = (ushort_t)(xw[k] >> 16);
        }
        float* arr = (seg < 2) ? &sB[buf][0][0] : &sC[buf][0][0];
        const int rbase = (seg & 1) * 8;
        const uint32_t bw[4] = { rbc.x, rbc.y, rbc.z, rbc.w };
#pragma unroll
        for (int k = 0; k < 4; k++) {
            arr[(rbase + 2 * k) * 68 + scol]     = b2f((ushort_t)(bw[k] & 0xffff));
            arr[(rbase + 2 * k + 1) * 68 + scol] = b2f((ushort_t)(bw[k] >> 16));
        }
    };
    auto flush = [&](int cm1) {
        const int bufm1 = cm1 & 1;
        int row = cm1 * 64 + stt;
        int orow = br ? (511 - row) : row;   // store at original-time row
        const uint32_t zw[4] = { rz_f.x, rz_f.y, rz_f.z, rz_f.w };
        float zv[8];
#pragma unroll
        for (int k = 0; k < 4; k++) {
            zv[2 * k]     = b2f((ushort_t)(zw[k] & 0xffff));
            zv[2 * k + 1] = b2f((ushort_t)(zw[k] >> 16));
        }
        float4 p0 = *(const float4*)(&sy[bufm1][stt][seg * 8]);
        float4 p1 = *(const float4*)(&sy[bufm1][stt][seg * 8 + 4]);
        const float pv[8] = { p0.x, p0.y, p0.z, p0.w, p1.x, p1.y, p1.z, p1.w };
        const uint32_t xw[4] = { rx_f.x, rx_f.y, rx_f.z, rx_f.w };
        float xvv[8];
#pragma unroll
        for (int k = 0; k < 4; k++) {
            xvv[2 * k]     = b2f((ushort_t)(xw[k] & 0xffff));
            xvv[2 * k + 1] = b2f((ushort_t)(xw[k] >> 16));
        }
        const float Dv[8] = { rD0.x, rD0.y, rD0.z, rD0.w, rD1.x, rD1.y, rD1.z, rD1.w };
        uint32_t op[4];
#pragma unroll
        for (int k = 0; k < 4; k++) {
            float ga = (pv[2 * k]     + Dv[2 * k]     * xvv[2 * k])     *
                       (zv[2 * k]     / (1.f + __expf(-zv[2 * k])));
            float gb = (pv[2 * k + 1] + Dv[2 * k + 1] * xvv[2 * k + 1]) *
                       (zv[2 * k + 1] / (1.f + __expf(-zv[2 * k + 1])));
            op[k] = (uint32_t)f2b(ga) | ((uint32_t)f2b(gb) << 16);
        }
        *(uint4*)(y + (size_t)orow * 2048 + e0 + seg * 8) =
            make_uint4(op[0], op[1], op[2], op[3]);
    };

    float h0 = 0.f, h1 = 0.f;
    const int sw = ((el >> 3) & 3) * 8;    // read-side xor (wave-uniform)

    load_regs(0);
    write_lds(0);
    rx_c = rx; rz_c = rz;

    for (int c = 0; c < 8; ++c) {
        if (c < 7) load_regs(c + 1);
        __syncthreads();
        const int buf = c & 1;

#pragma unroll 4
        for (int tq = 0; tq < 64; tq += 4) {
            const int tc = tq ^ sw;
            float4 dv = *(const float4*)(&sd[buf][el][tc]);
            uint2  xv = *(const uint2*)(&sx[buf][el][tc]);
            float4 B0 = *(const float4*)(&sB[buf][n2][tq]);
            float4 B1 = *(const float4*)(&sB[buf][n2 + 8][tq ^ 8]);
            float4 C0 = *(const float4*)(&sC[buf][n2][tq ^ 16]);
            float4 C1 = *(const float4*)(&sC[buf][n2 + 8][tq ^ 24]);

            float x0 = b2f((ushort_t)(xv.x & 0xffff));
            float x1 = b2f((ushort_t)(xv.x >> 16));
            float x2 = b2f((ushort_t)(xv.y & 0xffff));
            float x3 = b2f((ushort_t)(xv.y >> 16));

            float e00 = EXP2(dv.x * A0), e01 = EXP2(dv.y * A0);
            float e02 = EXP2(dv.z * A0), e03 = EXP2(dv.w * A0);
            float e10 = EXP2(dv.x * A1), e11 = EXP2(dv.y * A1);
            float e12 = EXP2(dv.z * A1), e13 = EXP2(dv.w * A1);

            float dx0 = dv.x * x0, dx1 = dv.y * x1;
            float dx2 = dv.z * x2, dx3 = dv.w * x3;

            h0 = e00 * h0 + dx0 * B0.x;  h1 = e10 * h1 + dx0 * B1.x;
            float p0 = h0 * C0.x + h1 * C1.x;
            h0 = e01 * h0 + dx1 * B0.y;  h1 = e11 * h1 + dx1 * B1.y;
            float p1 = h0 * C0.y + h1 * C1.y;
            h0 = e02 * h0 + dx2 * B0.z;  h1 = e12 * h1 + dx2 * B1.z;
            float p2 = h0 * C0.z + h1 * C1.z;
            h0 = e03 * h0 + dx3 * B0.w;  h1 = e13 * h1 + dx3 * B1.w;
            float p3 = h0 * C0.w + h1 * C1.w;

            p0 = dpp_add<DPP_XOR1>(p0); p0 = dpp_add<DPP_XOR2>(p0); p0 = dpp_add<DPP_HMIR>(p0);
            p1 = dpp_add<DPP_XOR1>(p1); p1 = dpp_add<DPP_XOR2>(p1); p1 = dpp_add<DPP_HMIR>(p1);
            p2 = dpp_add<DPP_XOR1>(p2); p2 = dpp_add<DPP_XOR2>(p2); p2 = dpp_add<DPP_HMIR>(p2);
            p3 = dpp_add<DPP_XOR1>(p3); p3 = dpp_add<DPP_XOR2>(p3); p3 = dpp_add<DPP_HMIR>(p3);

            if (n2 == 0) {
                sy[buf][tq + 0][el] = p0;
                sy[buf][tq + 1][el] = p1;
                sy[buf][tq + 2][el] = p2;
                sy[buf][tq + 3][el] = p3;
            }
        }

        if (c > 0) flush(c - 1);

        if (c < 7) {
            write_lds((c + 1) & 1);
            rx_f = rx_c; rz_f = rz_c;
            rx_c = rx;   rz_c = rz;
        } else {
            rx_f = rx_c; rz_f = rz_c;
        }
    }
    __syncthreads();
    flush(7);
}

// ---------------------------------------------------------------------------
// Workspace layout (bytes)
// ---------------------------------------------------------------------------
static const size_t TT = 2048;  // B_SZ * L
static const size_t OFF_XZ16  = 0;                          // 16MB
static const size_t OFF_XC16  = OFF_XZ16  + TT*4096*2;      // 16MB
static const size_t OFF_DBC16 = OFF_XC16  + 2*TT*2048*2;    // .75MB
static const size_t OFF_DELTA = OFF_DBC16 + 2*TT*96*2;      // 16MB
static const size_t OFF_YF    = OFF_DELTA + 2*TT*2048*2;    // 8MB
static const size_t OFF_YB    = OFF_YF    + TT*2048*2;      // 8MB
static const size_t OFF_X16   = OFF_YB    + TT*2048*2;      // 4MB
static const size_t OFF_WIN16 = OFF_X16   + TT*1024*2;      // 8MB
static const size_t OFF_WX16  = OFF_WIN16 + 4096*1024*2;    // .75MB
static const size_t OFF_WDT16 = OFF_WX16  + 2*96*2048*2;    // .5MB
static const size_t OFF_WOUT16= OFF_WDT16 + 2*2048*64*2;    // 4MB
static const size_t OFF_PART  = OFF_WOUT16+ 1024*2048*2;    // 12.6MB

extern "C" void kernel_launch(void* const* d_in, const int* in_sizes, int n_in,
                              void* d_out, int out_size, void* d_ws, size_t ws_size,
                              hipStream_t stream) {
    const float* x       = (const float*)d_in[0];
    const float* W_in    = (const float*)d_in[1];
    const float* conv_w  = (const float*)d_in[2];
    const float* conv_b  = (const float*)d_in[3];
    const float* Wx      = (const float*)d_in[4];
    const float* Wdt     = (const float*)d_in[5];
    const float* b_dt    = (const float*)d_in[6];
    const float* A_log   = (const float*)d_in[7];
    const float* Dp      = (const float*)d_in[8];
    const float* conv_w_b= (const float*)d_in[9];
    const float* conv_b_b= (const float*)d_in[10];
    const float* Wx_b    = (const float*)d_in[11];
    const float* Wdt_b   = (const float*)d_in[12];
    const float* b_dt_b  = (const float*)d_in[13];
    const float* A_log_b = (const float*)d_in[14];
    const float* Dp_b    = (const float*)d_in[15];
    const float* W_out   = (const float*)d_in[16];
    float* out = (float*)d_out;

    char* ws = (char*)d_ws;
    ushort_t* xz16  = (ushort_t*)(ws + OFF_XZ16);
    ushort_t* xc16  = (ushort_t*)(ws + OFF_XC16);
    ushort_t* dbc16 = (ushort_t*)(ws + OFF_DBC16);
    ushort_t* delta = (ushort_t*)(ws + OFF_DELTA);
    ushort_t* yf    = (ushort_t*)(ws + OFF_YF);
    ushort_t* yb    = (ushort_t*)(ws + OFF_YB);
    ushort_t* x16   = (ushort_t*)(ws + OFF_X16);
    ushort_t* win16 = (ushort_t*)(ws + OFF_WIN16);
    ushort_t* wx16  = (ushort_t*)(ws + OFF_WX16);
    ushort_t* wdt16 = (ushort_t*)(ws + OFF_WDT16);
    ushort_t* wout16= (ushort_t*)(ws + OFF_WOUT16);
    float*    part  = (float*)(ws + OFF_PART);

    dim3 blk(256);

    CastArgs ca;
    const int n4s[7] = {524288, 1048576, 49152, 49152, 32768, 32768, 524288};
    ca.seg[0] = { (const float4*)x,     (ushort4*)x16 };
    ca.seg[1] = { (const float4*)W_in,  (ushort4*)win16 };
    ca.seg[2] = { (const float4*)Wx,    (ushort4*)wx16 };
    ca.seg[3] = { (const float4*)Wx_b,  (ushort4*)(wx16 + 96 * 2048) };
    ca.seg[4] = { (const float4*)Wdt,   (ushort4*)wdt16 };
    ca.seg[5] = { (const float4*)Wdt_b, (ushort4*)(wdt16 + 2048 * 64) };
    ca.seg[6] = { (const float4*)W_out, (ushort4*)wout16 };
    ca.start[0] = 0;
    for (int i = 0; i < 7; i++) ca.start[i + 1] = ca.start[i] + n4s[i];
    cast_multi<<<(ca.start[7] + 255) / 256, blk, 0, stream>>>(ca);

    gemm_g1<<<dim3(32, 16), blk, 0, stream>>>(x16, 1024, win16, 1024, xz16, 4096, 1024);

    conv_silu_kernel<<<4096, blk, 0, stream>>>(xz16, conv_w, conv_b, conv_w_b, conv_b_b, xc16);

    gemm_g2<<<dim3(8, 16, 2), blk, 0, stream>>>(xc16, wx16, part);
    reduce_dbc<<<384, blk, 0, stream>>>((const float4*)part, (ushort4*)dbc16);

    gemm_g3<<<dim3(16, 16, 2), blk, 0, stream>>>(dbc16, wdt16, delta, b_dt, b_dt_b);

    scan_kernel<<<512, blk, 0, stream>>>(delta, xc16, dbc16, xz16, A_log, A_log_b, Dp, Dp_b, yf, yb);

    // G4 with fused combine: out = 0.5*(yf+yb) @ W_out^T
    gemm_g4<<<dim3(8, 32), blk, 0, stream>>>(yf, yb, wout16, 2048, out, 1024, 2048);
}

// Round 9
// 295.223 us; speedup vs baseline: 1.0072x; 1.0072x over previous
//
#include <hip/hip_runtime.h>
#include <hip/hip_bf16.h>
#include <stdint.h>

typedef unsigned short ushort_t;
typedef __attribute__((ext_vector_type(8))) short short8;
typedef __attribute__((ext_vector_type(4))) float f32x4;

__device__ __forceinline__ float b2f(ushort_t u) {
    union { uint32_t i; float f; } v; v.i = ((uint32_t)u) << 16; return v.f;
}
__device__ __forceinline__ ushort_t f2b(float f) {
    union { float f; uint32_t i; } v; v.f = f;
    uint32_t r = v.i + 0x7fff + ((v.i >> 16) & 1);
    return (ushort_t)(r >> 16);
}

#if __has_builtin(__builtin_amdgcn_exp2f)
#define EXP2(x) __builtin_amdgcn_exp2f(x)
#else
#define EXP2(x) __expf((x) * 0.69314718056f)
#endif

// async global->LDS, 16B per lane; lds base must be wave-uniform
__device__ __forceinline__ void ll16(const ushort_t* g, ushort_t* l) {
    __builtin_amdgcn_global_load_lds(
        (const __attribute__((address_space(1))) uint32_t*)g,
        (__attribute__((address_space(3))) uint32_t*)l, 16, 0, 0);
}

// DPP cross-lane add (VALU pipe)
template <int CTRL>
__device__ __forceinline__ float dpp_add(float p) {
    int v = __builtin_amdgcn_update_dpp(0, __float_as_int(p), CTRL, 0xF, 0xF, true);
    return p + __int_as_float(v);
}
#define DPP_XOR1 0xB1
#define DPP_XOR2 0x4E
#define DPP_HMIR 0x141

// ---------------------------------------------------------------------------
// Coalesced epilogues: wave's 16x64 output group via private LDS scratch.
// ---------------------------------------------------------------------------
__device__ __forceinline__ void epi_wave_f32(
    float* sw, const f32x4* accg, float* dst0, int ldc, int lane)
{
    const int quad = lane >> 4, lr = lane & 15;
#pragma unroll
    for (int j = 0; j < 4; j++)
#pragma unroll
        for (int r = 0; r < 4; r++)
            sw[(quad * 4 + r) * 64 + j * 16 + lr] = accg[j][r];
    __asm__ volatile("s_waitcnt lgkmcnt(0)" ::: "memory");
#pragma unroll
    for (int t = 0; t < 4; t++) {
        int row = t * 4 + quad;
        float4 v = *(const float4*)(&sw[row * 64 + lr * 4]);
        *(float4*)(dst0 + (size_t)row * ldc + lr * 4) = v;
    }
}

__device__ __forceinline__ void epi_wave_b16(
    float* sw, const f32x4* accg, ushort_t* dst0, int ldc, int lane)
{
    const int quad = lane >> 4, lr = lane & 15;
#pragma unroll
    for (int j = 0; j < 4; j++)
#pragma unroll
        for (int r = 0; r < 4; r++)
            sw[(quad * 4 + r) * 64 + j * 16 + lr] = accg[j][r];
    __asm__ volatile("s_waitcnt lgkmcnt(0)" ::: "memory");
#pragma unroll
    for (int t = 0; t < 4; t++) {
        int row = t * 4 + quad;
        float4 v = *(const float4*)(&sw[row * 64 + lr * 4]);
        ushort4 o; o.x = f2b(v.x); o.y = f2b(v.y); o.z = f2b(v.z); o.w = f2b(v.w);
        *(ushort4*)(dst0 + (size_t)row * ldc + lr * 4) = o;
    }
}

// ---------------------------------------------------------------------------
// Fused multi-tensor fp32 -> bf16 cast (7 segments, 1 launch)
// ---------------------------------------------------------------------------
struct CastSeg { const float4* src; ushort4* dst; };
struct CastArgs { CastSeg seg[7]; int start[8]; };

__global__ __launch_bounds__(256) void cast_multi(CastArgs a)
{
    int g = blockIdx.x * 256 + threadIdx.x;
    if (g >= a.start[7]) return;
    int s = 0;
#pragma unroll
    for (int i = 1; i < 7; i++) s += (g >= a.start[i]);
    int i = g - a.start[s];
    float4 v = a.seg[s].src[i];
    ushort4 o;
    o.x = f2b(v.x); o.y = f2b(v.y); o.z = f2b(v.z); o.w = f2b(v.w);
    a.seg[s].dst[i] = o;
}

#define BK 32

// ---------------------------------------------------------------------------
// G1: xz16 = x @ W_in^T (2048 x 4096, K=1024), bf16 out, coalesced epilogue.
// ---------------------------------------------------------------------------
__global__ __launch_bounds__(256) void gemm_g1(
    const ushort_t* __restrict__ A, int lda,
    const ushort_t* __restrict__ B, int ldb,
    ushort_t* __restrict__ Cout, int ldc, int Kd)
{
    __shared__ ushort_t As[128 * BK];
    __shared__ ushort_t Bs[128 * BK];
    __shared__ float sepi[4][1024];

    const int tid  = threadIdx.x;
    const int m0   = blockIdx.y * 128;
    const int n0   = blockIdx.x * 128;
    const int wv   = tid >> 6;
    const int lane = tid & 63;
    const int wm   = (wv >> 1) * 64;
    const int wn   = (wv & 1) * 64;
    const int lr   = lane & 15;
    const int quad = lane >> 4;

    f32x4 acc[4][4];
#pragma unroll
    for (int i = 0; i < 4; i++)
#pragma unroll
        for (int j = 0; j < 4; j++) acc[i][j] = f32x4{0.f, 0.f, 0.f, 0.f};

    const int srA = wv * 32 + (lane >> 2);
    const int scA = (lane & 3) * 8;

    for (int k0 = 0; k0 < Kd; k0 += BK) {
        ll16(A + (size_t)(m0 + srA) * lda + k0 + scA,      &As[wv * 1024]);
        ll16(A + (size_t)(m0 + srA + 16) * lda + k0 + scA, &As[wv * 1024 + 512]);
        ll16(B + (size_t)(n0 + srA) * ldb + k0 + scA,      &Bs[wv * 1024]);
        ll16(B + (size_t)(n0 + srA + 16) * ldb + k0 + scA, &Bs[wv * 1024 + 512]);
        __syncthreads();

        short8 af[4], bf[4];
#pragma unroll
        for (int i = 0; i < 4; i++)
            af[i] = *(const short8*)(&As[(wm + i * 16 + lr) * BK + quad * 8]);
#pragma unroll
        for (int j = 0; j < 4; j++)
            bf[j] = *(const short8*)(&Bs[(wn + j * 16 + lr) * BK + quad * 8]);
#pragma unroll
        for (int i = 0; i < 4; i++)
#pragma unroll
            for (int j = 0; j < 4; j++)
                acc[i][j] = __builtin_amdgcn_mfma_f32_16x16x32_bf16(af[i], bf[j], acc[i][j], 0, 0, 0);
        __syncthreads();
    }

#pragma unroll
    for (int g = 0; g < 4; g++)
        epi_wave_b16(sepi[wv], acc[g],
                     Cout + (size_t)(m0 + wm + g * 16) * ldc + n0 + wn, ldc, lane);
}

// ---------------------------------------------------------------------------
// G4: out = yc @ W_out^T (2048 x 1024, K=2048), fp32 out, BM=64, ll16 staging.
// ---------------------------------------------------------------------------
__global__ __launch_bounds__(256) void gemm_g4(
    const ushort_t* __restrict__ A, int lda,
    const ushort_t* __restrict__ B, int ldb,
    float* __restrict__ Cout, int ldc, int Kd)
{
    __shared__ ushort_t As[64 * BK];
    __shared__ ushort_t Bs[128 * BK];
    __shared__ float sepi[4][1024];

    const int tid  = threadIdx.x;
    const int m0   = blockIdx.y * 64;
    const int n0   = blockIdx.x * 128;
    const int wv   = tid >> 6;
    const int lane = tid & 63;
    const int wm   = (wv >> 1) * 32;
    const int wn   = (wv & 1) * 64;
    const int lr   = lane & 15;
    const int quad = lane >> 4;

    f32x4 acc[2][4];
#pragma unroll
    for (int i = 0; i < 2; i++)
#pragma unroll
        for (int j = 0; j < 4; j++) acc[i][j] = f32x4{0.f, 0.f, 0.f, 0.f};

    const int srA = wv * 16 + (lane >> 2);
    const int srB = wv * 32 + (lane >> 2);
    const int sc  = (lane & 3) * 8;

    for (int k0 = 0; k0 < Kd; k0 += BK) {
        ll16(A + (size_t)(m0 + srA) * lda + k0 + sc,      &As[wv * 512]);
        ll16(B + (size_t)(n0 + srB) * ldb + k0 + sc,      &Bs[wv * 1024]);
        ll16(B + (size_t)(n0 + srB + 16) * ldb + k0 + sc, &Bs[wv * 1024 + 512]);
        __syncthreads();

        short8 af[2], bf[4];
#pragma unroll
        for (int i = 0; i < 2; i++)
            af[i] = *(const short8*)(&As[(wm + i * 16 + lr) * BK + quad * 8]);
#pragma unroll
        for (int j = 0; j < 4; j++)
            bf[j] = *(const short8*)(&Bs[(wn + j * 16 + lr) * BK + quad * 8]);
#pragma unroll
        for (int i = 0; i < 2; i++)
#pragma unroll
            for (int j = 0; j < 4; j++)
                acc[i][j] = __builtin_amdgcn_mfma_f32_16x16x32_bf16(af[i], bf[j], acc[i][j], 0, 0, 0);
        __syncthreads();
    }

#pragma unroll
    for (int g = 0; g < 2; g++)
        epi_wave_f32(sepi[wv], acc[g],
                     Cout + (size_t)(m0 + wm + g * 16) * ldc + n0 + wn, ldc, lane);
}

// ---------------------------------------------------------------------------
// G2: dbc partials. grid (SK=8, M/128=16, br=2). N=96, guarded coalesced epi.
// ---------------------------------------------------------------------------
__global__ __launch_bounds__(256) void gemm_g2(
    const ushort_t* __restrict__ xc, const ushort_t* __restrict__ wx,
    float* __restrict__ part)
{
    __shared__ ushort_t As[128 * BK];
    __shared__ ushort_t Bs[128 * BK];
    __shared__ float sepi[4][1024];

    const int sk = blockIdx.x, mb = blockIdx.y, br = blockIdx.z;
    const ushort_t* A = xc + (size_t)br * 2048 * 2048;
    const ushort_t* B = wx + (size_t)br * 96 * 2048;
    float* C = part + (size_t)(sk * 2 + br) * 2048 * 96;
    const int m0 = mb * 128;
    const int kb = sk * 256;

    const int tid  = threadIdx.x;
    const int wv   = tid >> 6;
    const int lane = tid & 63;
    const int wm   = (wv >> 1) * 64;
    const int wn   = (wv & 1) * 64;
    const int lr   = lane & 15;
    const int quad = lane >> 4;

    f32x4 acc[4][4];
#pragma unroll
    for (int i = 0; i < 4; i++)
#pragma unroll
        for (int j = 0; j < 4; j++) acc[i][j] = f32x4{0.f, 0.f, 0.f, 0.f};

    const int srA = wv * 32 + (lane >> 2);
    const int sc  = (lane & 3) * 8;

    for (int k0 = kb; k0 < kb + 256; k0 += BK) {
        ll16(A + (size_t)(m0 + srA) * 2048 + k0 + sc,      &As[wv * 1024]);
        ll16(A + (size_t)(m0 + srA + 16) * 2048 + k0 + sc, &As[wv * 1024 + 512]);
        ll16(B + (size_t)(srA) * 2048 + k0 + sc,           &Bs[wv * 1024]);
        ll16(B + (size_t)(srA + 16) * 2048 + k0 + sc,      &Bs[wv * 1024 + 512]);
        __syncthreads();

        short8 af[4], bf[4];
#pragma unroll
        for (int i = 0; i < 4; i++)
            af[i] = *(const short8*)(&As[(wm + i * 16 + lr) * BK + quad * 8]);
#pragma unroll
        for (int j = 0; j < 4; j++)
            bf[j] = *(const short8*)(&Bs[(wn + j * 16 + lr) * BK + quad * 8]);
#pragma unroll
        for (int i = 0; i < 4; i++)
#pragma unroll
            for (int j = 0; j < 4; j++)
                acc[i][j] = __builtin_amdgcn_mfma_f32_16x16x32_bf16(af[i], bf[j], acc[i][j], 0, 0, 0);
        __syncthreads();
    }

    float* sw = sepi[wv];
#pragma unroll
    for (int g = 0; g < 4; g++) {
#pragma unroll
        for (int j = 0; j < 4; j++)
#pragma unroll
            for (int r = 0; r < 4; r++)
                sw[(quad * 4 + r) * 64 + j * 16 + lr] = acc[g][j][r];
        __asm__ volatile("s_waitcnt lgkmcnt(0)" ::: "memory");
        int col = wn + lr * 4;
#pragma unroll
        for (int t = 0; t < 4; t++) {
            int row = t * 4 + quad;
            if (col < 96) {
                float4 v = *(const float4*)(&sw[row * 64 + lr * 4]);
                *(float4*)(C + (size_t)(m0 + wm + g * 16 + row) * 96 + col) = v;
            }
        }
    }
}

__global__ __launch_bounds__(256) void reduce_dbc(
    const float4* __restrict__ part, ushort4* __restrict__ dbc16)
{
    int g = blockIdx.x * 256 + threadIdx.x;   // 98304 total
    const int S = 2 * 2048 * 96 / 4;
    float4 r = part[g];
#pragma unroll
    for (int i = 1; i < 8; i++) {
        float4 p = part[g + i * S];
        r.x += p.x; r.y += p.y; r.z += p.z; r.w += p.w;
    }
    ushort4 o; o.x = f2b(r.x); o.y = f2b(r.y); o.z = f2b(r.z); o.w = f2b(r.w);
    dbc16[g] = o;
}

// ---------------------------------------------------------------------------
// G3: delta16 = softplus(dbc[:, :64] @ Wdt^T + b_dt), bf16 out, fast softplus.
// ---------------------------------------------------------------------------
__global__ __launch_bounds__(256) void gemm_g3(
    const ushort_t* __restrict__ dbc16, const ushort_t* __restrict__ wdt,
    ushort_t* __restrict__ delta,
    const float* __restrict__ bdt_f, const float* __restrict__ bdt_b)
{
    __shared__ ushort_t As[128 * BK];
    __shared__ ushort_t Bs[128 * BK];
    __shared__ float sepi[4][1024];

    const int br = blockIdx.z;
    const ushort_t* A = dbc16 + (size_t)br * 2048 * 96;
    const ushort_t* B = wdt + (size_t)br * 2048 * 64;
    ushort_t* C = delta + (size_t)br * 2048 * 2048;
    const float* bias = br ? bdt_b : bdt_f;

    const int tid  = threadIdx.x;
    const int m0   = blockIdx.y * 128;
    const int n0   = blockIdx.x * 128;
    const int wv   = tid >> 6;
    const int lane = tid & 63;
    const int wm   = (wv >> 1) * 64;
    const int wn   = (wv & 1) * 64;
    const int lr   = lane & 15;
    const int quad = lane >> 4;

    f32x4 acc[4][4];
#pragma unroll
    for (int i = 0; i < 4; i++)
#pragma unroll
        for (int j = 0; j < 4; j++) acc[i][j] = f32x4{0.f, 0.f, 0.f, 0.f};

    const int srA = wv * 32 + (lane >> 2);
    const int sc  = (lane & 3) * 8;

    for (int k0 = 0; k0 < 64; k0 += BK) {
        ll16(A + (size_t)(m0 + srA) * 96 + k0 + sc,       &As[wv * 1024]);
        ll16(A + (size_t)(m0 + srA + 16) * 96 + k0 + sc,  &As[wv * 1024 + 512]);
        ll16(B + (size_t)(n0 + srA) * 64 + k0 + sc,       &Bs[wv * 1024]);
        ll16(B + (size_t)(n0 + srA + 16) * 64 + k0 + sc,  &Bs[wv * 1024 + 512]);
        __syncthreads();

        short8 af[4], bf[4];
#pragma unroll
        for (int i = 0; i < 4; i++)
            af[i] = *(const short8*)(&As[(wm + i * 16 + lr) * BK + quad * 8]);
#pragma unroll
        for (int j = 0; j < 4; j++)
            bf[j] = *(const short8*)(&Bs[(wn + j * 16 + lr) * BK + quad * 8]);
#pragma unroll
        for (int i = 0; i < 4; i++)
#pragma unroll
            for (int j = 0; j < 4; j++)
                acc[i][j] = __builtin_amdgcn_mfma_f32_16x16x32_bf16(af[i], bf[j], acc[i][j], 0, 0, 0);
        __syncthreads();
    }

    float bn[4];
#pragma unroll
    for (int j = 0; j < 4; j++) bn[j] = bias[n0 + wn + j * 16 + lr];
#pragma unroll
    for (int g = 0; g < 4; g++)
#pragma unroll
        for (int j = 0; j < 4; j++)
#pragma unroll
            for (int r = 0; r < 4; r++) {
                float x = acc[g][j][r] + bn[j];
                float sp = fmaxf(x, 0.f) + __logf(1.f + __expf(-fabsf(x)));
                acc[g][j][r] = sp;
            }

#pragma unroll
    for (int g = 0; g < 4; g++)
        epi_wave_b16(sepi[wv], acc[g],
                     C + (size_t)(m0 + wm + g * 16) * 2048 + n0 + wn, 2048, lane);
}

// ---------------------------------------------------------------------------
// Causal depthwise conv (K=4) + bias + silu, vectorized: thread = 8 e's.
// ---------------------------------------------------------------------------
__global__ __launch_bounds__(256) void conv_silu_kernel(
    const ushort_t* __restrict__ xz,
    const float* __restrict__ w_f, const float* __restrict__ cb_f,
    const float* __restrict__ w_b, const float* __restrict__ cb_b,
    ushort_t* __restrict__ xc16)
{
    int g = blockIdx.x * 256 + threadIdx.x;   // 1048576 total
    int e8 = g & 255;
    int t  = (g >> 8) & 511;
    int b  = (g >> 17) & 3;
    int br = g >> 19;
    int e  = e8 * 8;

    const float* w  = br ? w_b  : w_f;
    const float* cb = br ? cb_b : cb_f;

    float acc[8];
#pragma unroll
    for (int j = 0; j < 8; j++) acc[j] = cb[e + j];
    float4 wv[8];
#pragma unroll
    for (int j = 0; j < 8; j++) wv[j] = *(const float4*)(w + (e + j) * 4);

#pragma unroll
    for (int k = 0; k < 4; k++) {
        int tp = t - 3 + k;
        if (tp >= 0) {
            int row = br ? (511 - tp) : tp;
            uint4 u = *(const uint4*)(xz + ((size_t)(b * 512 + row)) * 4096 + e);
            const uint32_t uw[4] = { u.x, u.y, u.z, u.w };
#pragma unroll
            for (int q = 0; q < 4; q++) {
                float v0 = b2f((ushort_t)(uw[q] & 0xffff));
                float v1 = b2f((ushort_t)(uw[q] >> 16));
                const float* wq0 = (const float*)&wv[2 * q];
                const float* wq1 = (const float*)&wv[2 * q + 1];
                acc[2 * q]     += wq0[k] * v0;
                acc[2 * q + 1] += wq1[k] * v1;
            }
        }
    }
    uint32_t ow[4];
#pragma unroll
    for (int q = 0; q < 4; q++) {
        float s0 = acc[2 * q]     / (1.f + __expf(-acc[2 * q]));
        float s1 = acc[2 * q + 1] / (1.f + __expf(-acc[2 * q + 1]));
        ow[q] = (uint32_t)f2b(s0) | ((uint32_t)f2b(s1) << 16);
    }
    *(uint4*)(xc16 + ((size_t)(br * 4 + b) * 512 + t) * 2048 + e) =
        make_uint4(ow[0], ow[1], ow[2], ow[3]);
}

// ---------------------------------------------------------------------------
// Selective scan v8: y stored at ORIGINAL-time rows for both branches.
// ---------------------------------------------------------------------------
__global__ __launch_bounds__(256) void scan_kernel(
    const ushort_t* __restrict__ delta,   // [2][B][L][ED] bf16
    const ushort_t* __restrict__ xc,      // [2][B][L][ED] bf16
    const ushort_t* __restrict__ dbc16,   // [2][B][L][96] bf16
    const ushort_t* __restrict__ xz,      // [B][L][4096] bf16 (z half)
    const float* __restrict__ Alog_f, const float* __restrict__ Alog_b,
    const float* __restrict__ Dp_f,   const float* __restrict__ Dp_b,
    ushort_t* __restrict__ yf, ushort_t* __restrict__ yb)
{
    const int blk = blockIdx.x;            // 0..511
    const int eg = blk & 63;
    const int b  = (blk >> 6) & 3;
    const int br = blk >> 8;
    const int e0 = eg * 32;

    const int tid = threadIdx.x;
    const int n2  = tid & 7;
    const int el  = tid >> 3;              // 0..31
    const int e   = e0 + el;

    const float* Alog = br ? Alog_b : Alog_f;
    const float* Dpp  = br ? Dp_b   : Dp_f;
    const float A0 = -__expf(Alog[e * 16 + n2]) * 1.44269504f;
    const float A1 = -__expf(Alog[e * 16 + n2 + 8]) * 1.44269504f;

    size_t tb = ((size_t)br * 4 + b) * 512;
    const ushort_t* dlt  = delta + tb * 2048;
    const ushort_t* xcb  = xc    + tb * 2048;
    const ushort_t* dbcb = dbc16 + tb * 96;
    ushort_t* y = (br ? yb : yf) + (size_t)b * 512 * 2048;

    __shared__ float    sd[2][32][68];     // d[e][t^swz]
    __shared__ ushort_t sx[2][32][72];     // x[e][t^swz]
    __shared__ float    sB[2][16][68];     // B[n][t^swz] fp32
    __shared__ float    sC[2][16][68];     // C[n][t^swz] fp32
    __shared__ float    sy[2][64][36];     // y[t][e], ping-pong

    const int stt = tid >> 2;              // 0..63 (t within chunk)
    const int seg = tid & 3;               // 8-elem column group
    const int swz = seg * 8;
    const int scol = stt ^ swz;

    float4 rD0 = *(const float4*)(Dpp + e0 + seg * 8);
    float4 rD1 = *(const float4*)(Dpp + e0 + seg * 8 + 4);

    uint4 rdx, rx, rbc, rz;
    uint4 rx_c, rx_f, rz_c, rz_f;

    auto load_regs = [&](int c) {
        int t0 = c * 64;
        rdx = *(const uint4*)(dlt + (size_t)(t0 + stt) * 2048 + e0 + seg * 8);
        rx  = *(const uint4*)(xcb + (size_t)(t0 + stt) * 2048 + e0 + seg * 8);
        rbc = *(const uint4*)(dbcb + (size_t)(t0 + stt) * 96 + 64 + seg * 8);
        int orow = br ? (511 - (t0 + stt)) : (t0 + stt);
        rz  = *(const uint4*)(xz + ((size_t)(b * 512 + orow)) * 4096 + 2048 + e0 + seg * 8);
    };
    auto write_lds = [&](int buf) {
        const uint32_t dw[4] = { rdx.x, rdx.y, rdx.z, rdx.w };
#pragma unroll
        for (int k = 0; k < 4; k++) {
            sd[buf][seg * 8 + 2 * k][scol]     = b2f((ushort_t)(dw[k] & 0xffff));
            sd[buf][seg * 8 + 2 * k + 1][scol] = b2f((ushort_t)(dw[k] >> 16));
        }
        const uint32_t xw[4] = { rx.x, rx.y, rx.z, rx.w };
#pragma unroll
        for (int k = 0; k < 4; k++) {
            sx[buf][seg * 8 + 2 * k][scol]     = (ushort_t)(xw[k] & 0xffff);
            sx[buf][seg * 8 + 2 * k + 1][scol] = (ushort_t)(xw[k] >> 16);
        }
        float* arr = (seg < 2) ? &sB[buf][0][0] : &sC[buf][0][0];
        const int rbase = (seg & 1) * 8;
        const uint32_t bw[4] = { rbc.x, rbc.y, rbc.z, rbc.w };
#pragma unroll
        for (int k = 0; k < 4; k++) {
            arr[(rbase + 2 * k) * 68 + scol]     = b2f((ushort_t)(bw[k] & 0xffff));
            arr[(rbase + 2 * k + 1) * 68 + scol] = b2f((ushort_t)(bw[k] >> 16));
        }
    };
    auto flush = [&](int cm1) {
        const int bufm1 = cm1 & 1;
        int row = cm1 * 64 + stt;
        int orow = br ? (511 - row) : row;   // store at original-time row
        const uint32_t zw[4] = { rz_f.x, rz_f.y, rz_f.z, rz_f.w };
        float zv[8];
#pragma unroll
        for (int k = 0; k < 4; k++) {
            zv[2 * k]     = b2f((ushort_t)(zw[k] & 0xffff));
            zv[2 * k + 1] = b2f((ushort_t)(zw[k] >> 16));
        }
        float4 p0 = *(const float4*)(&sy[bufm1][stt][seg * 8]);
        float4 p1 = *(const float4*)(&sy[bufm1][stt][seg * 8 + 4]);
        const float pv[8] = { p0.x, p0.y, p0.z, p0.w, p1.x, p1.y, p1.z, p1.w };
        const uint32_t xw[4] = { rx_f.x, rx_f.y, rx_f.z, rx_f.w };
        float xvv[8];
#pragma unroll
        for (int k = 0; k < 4; k++) {
            xvv[2 * k]     = b2f((ushort_t)(xw[k] & 0xffff));
            xvv[2 * k + 1] = b2f((ushort_t)(xw[k] >> 16));
        }
        const float Dv[8] = { rD0.x, rD0.y, rD0.z, rD0.w, rD1.x, rD1.y, rD1.z, rD1.w };
        uint32_t op[4];
#pragma unroll
        for (int k = 0; k < 4; k++) {
            float ga = (pv[2 * k]     + Dv[2 * k]     * xvv[2 * k])     *
                       (zv[2 * k]     / (1.f + __expf(-zv[2 * k])));
            float gb = (pv[2 * k + 1] + Dv[2 * k + 1] * xvv[2 * k + 1]) *
                       (zv[2 * k + 1] / (1.f + __expf(-zv[2 * k + 1])));
            op[k] = (uint32_t)f2b(ga) | ((uint32_t)f2b(gb) << 16);
        }
        *(uint4*)(y + (size_t)orow * 2048 + e0 + seg * 8) =
            make_uint4(op[0], op[1], op[2], op[3]);
    };

    float h0 = 0.f, h1 = 0.f;
    const int sw = ((el >> 3) & 3) * 8;    // read-side xor (wave-uniform)

    load_regs(0);
    write_lds(0);
    rx_c = rx; rz_c = rz;

    for (int c = 0; c < 8; ++c) {
        if (c < 7) load_regs(c + 1);
        __syncthreads();
        const int buf = c & 1;

#pragma unroll 4
        for (int tq = 0; tq < 64; tq += 4) {
            const int tc = tq ^ sw;
            float4 dv = *(const float4*)(&sd[buf][el][tc]);
            uint2  xv = *(const uint2*)(&sx[buf][el][tc]);
            float4 B0 = *(const float4*)(&sB[buf][n2][tq]);
            float4 B1 = *(const float4*)(&sB[buf][n2 + 8][tq ^ 8]);
            float4 C0 = *(const float4*)(&sC[buf][n2][tq ^ 16]);
            float4 C1 = *(const float4*)(&sC[buf][n2 + 8][tq ^ 24]);

            float x0 = b2f((ushort_t)(xv.x & 0xffff));
            float x1 = b2f((ushort_t)(xv.x >> 16));
            float x2 = b2f((ushort_t)(xv.y & 0xffff));
            float x3 = b2f((ushort_t)(xv.y >> 16));

            float e00 = EXP2(dv.x * A0), e01 = EXP2(dv.y * A0);
            float e02 = EXP2(dv.z * A0), e03 = EXP2(dv.w * A0);
            float e10 = EXP2(dv.x * A1), e11 = EXP2(dv.y * A1);
            float e12 = EXP2(dv.z * A1), e13 = EXP2(dv.w * A1);

            float dx0 = dv.x * x0, dx1 = dv.y * x1;
            float dx2 = dv.z * x2, dx3 = dv.w * x3;

            h0 = e00 * h0 + dx0 * B0.x;  h1 = e10 * h1 + dx0 * B1.x;
            float p0 = h0 * C0.x + h1 * C1.x;
            h0 = e01 * h0 + dx1 * B0.y;  h1 = e11 * h1 + dx1 * B1.y;
            float p1 = h0 * C0.y + h1 * C1.y;
            h0 = e02 * h0 + dx2 * B0.z;  h1 = e12 * h1 + dx2 * B1.z;
            float p2 = h0 * C0.z + h1 * C1.z;
            h0 = e03 * h0 + dx3 * B0.w;  h1 = e13 * h1 + dx3 * B1.w;
            float p3 = h0 * C0.w + h1 * C1.w;

            p0 = dpp_add<DPP_XOR1>(p0); p0 = dpp_add<DPP_XOR2>(p0); p0 = dpp_add<DPP_HMIR>(p0);
            p1 = dpp_add<DPP_XOR1>(p1); p1 = dpp_add<DPP_XOR2>(p1); p1 = dpp_add<DPP_HMIR>(p1);
            p2 = dpp_add<DPP_XOR1>(p2); p2 = dpp_add<DPP_XOR2>(p2); p2 = dpp_add<DPP_HMIR>(p2);
            p3 = dpp_add<DPP_XOR1>(p3); p3 = dpp_add<DPP_XOR2>(p3); p3 = dpp_add<DPP_HMIR>(p3);

            if (n2 == 0) {
                sy[buf][tq + 0][el] = p0;
                sy[buf][tq + 1][el] = p1;
                sy[buf][tq + 2][el] = p2;
                sy[buf][tq + 3][el] = p3;
            }
        }

        if (c > 0) flush(c - 1);

        if (c < 7) {
            write_lds((c + 1) & 1);
            rx_f = rx_c; rz_f = rz_c;
            rx_c = rx;   rz_c = rz;
        } else {
            rx_f = rx_c; rz_f = rz_c;
        }
    }
    __syncthreads();
    flush(7);
}

// ---------------------------------------------------------------------------
// Combine: yc = 0.5*(yf + yb) — index-aligned (scan stores original-time rows)
// ---------------------------------------------------------------------------
__global__ __launch_bounds__(256) void combine_kernel(
    const uint2* __restrict__ yf, const uint2* __restrict__ yb,
    uint2* __restrict__ yc)
{
    int g = blockIdx.x * 256 + threadIdx.x;   // 1048576 total
    uint2 a = yf[g];
    uint2 c = yb[g];
    uint2 o;
    o.x = (uint32_t)f2b(0.5f * (b2f((ushort_t)(a.x & 0xffff)) + b2f((ushort_t)(c.x & 0xffff)))) |
          ((uint32_t)f2b(0.5f * (b2f((ushort_t)(a.x >> 16)) + b2f((ushort_t)(c.x >> 16)))) << 16);
    o.y = (uint32_t)f2b(0.5f * (b2f((ushort_t)(a.y & 0xffff)) + b2f((ushort_t)(c.y & 0xffff)))) |
          ((uint32_t)f2b(0.5f * (b2f((ushort_t)(a.y >> 16)) + b2f((ushort_t)(c.y >> 16)))) << 16);
    yc[g] = o;
}

// ---------------------------------------------------------------------------
// Workspace layout (bytes)
// ---------------------------------------------------------------------------
static const size_t TT = 2048;  // B_SZ * L
static const size_t OFF_XZ16  = 0;                          // 16MB
static const size_t OFF_XC16  = OFF_XZ16  + TT*4096*2;      // 16MB
static const size_t OFF_DBC16 = OFF_XC16  + 2*TT*2048*2;    // .75MB
static const size_t OFF_DELTA = OFF_DBC16 + 2*TT*96*2;      // 16MB
static const size_t OFF_YF    = OFF_DELTA + 2*TT*2048*2;    // 8MB
static const size_t OFF_YB    = OFF_YF    + TT*2048*2;      // 8MB
static const size_t OFF_YC16  = OFF_YB    + TT*2048*2;      // 8MB
static const size_t OFF_X16   = OFF_YC16  + TT*2048*2;      // 4MB
static const size_t OFF_WIN16 = OFF_X16   + TT*1024*2;      // 8MB
static const size_t OFF_WX16  = OFF_WIN16 + 4096*1024*2;    // .75MB
static const size_t OFF_WDT16 = OFF_WX16  + 2*96*2048*2;    // .5MB
static const size_t OFF_WOUT16= OFF_WDT16 + 2*2048*64*2;    // 4MB
static const size_t OFF_PART  = OFF_WOUT16+ 1024*2048*2;    // 12.6MB

extern "C" void kernel_launch(void* const* d_in, const int* in_sizes, int n_in,
                              void* d_out, int out_size, void* d_ws, size_t ws_size,
                              hipStream_t stream) {
    const float* x       = (const float*)d_in[0];
    const float* W_in    = (const float*)d_in[1];
    const float* conv_w  = (const float*)d_in[2];
    const float* conv_b  = (const float*)d_in[3];
    const float* Wx      = (const float*)d_in[4];
    const float* Wdt     = (const float*)d_in[5];
    const float* b_dt    = (const float*)d_in[6];
    const float* A_log   = (const float*)d_in[7];
    const float* Dp      = (const float*)d_in[8];
    const float* conv_w_b= (const float*)d_in[9];
    const float* conv_b_b= (const float*)d_in[10];
    const float* Wx_b    = (const float*)d_in[11];
    const float* Wdt_b   = (const float*)d_in[12];
    const float* b_dt_b  = (const float*)d_in[13];
    const float* A_log_b = (const float*)d_in[14];
    const float* Dp_b    = (const float*)d_in[15];
    const float* W_out   = (const float*)d_in[16];
    float* out = (float*)d_out;

    char* ws = (char*)d_ws;
    ushort_t* xz16  = (ushort_t*)(ws + OFF_XZ16);
    ushort_t* xc16  = (ushort_t*)(ws + OFF_XC16);
    ushort_t* dbc16 = (ushort_t*)(ws + OFF_DBC16);
    ushort_t* delta = (ushort_t*)(ws + OFF_DELTA);
    ushort_t* yf    = (ushort_t*)(ws + OFF_YF);
    ushort_t* yb    = (ushort_t*)(ws + OFF_YB);
    ushort_t* yc16  = (ushort_t*)(ws + OFF_YC16);
    ushort_t* x16   = (ushort_t*)(ws + OFF_X16);
    ushort_t* win16 = (ushort_t*)(ws + OFF_WIN16);
    ushort_t* wx16  = (ushort_t*)(ws + OFF_WX16);
    ushort_t* wdt16 = (ushort_t*)(ws + OFF_WDT16);
    ushort_t* wout16= (ushort_t*)(ws + OFF_WOUT16);
    float*    part  = (float*)(ws + OFF_PART);

    dim3 blk(256);

    CastArgs ca;
    const int n4s[7] = {524288, 1048576, 49152, 49152, 32768, 32768, 524288};
    ca.seg[0] = { (const float4*)x,     (ushort4*)x16 };
    ca.seg[1] = { (const float4*)W_in,  (ushort4*)win16 };
    ca.seg[2] = { (const float4*)Wx,    (ushort4*)wx16 };
    ca.seg[3] = { (const float4*)Wx_b,  (ushort4*)(wx16 + 96 * 2048) };
    ca.seg[4] = { (const float4*)Wdt,   (ushort4*)wdt16 };
    ca.seg[5] = { (const float4*)Wdt_b, (ushort4*)(wdt16 + 2048 * 64) };
    ca.seg[6] = { (const float4*)W_out, (ushort4*)wout16 };
    ca.start[0] = 0;
    for (int i = 0; i < 7; i++) ca.start[i + 1] = ca.start[i] + n4s[i];
    cast_multi<<<(ca.start[7] + 255) / 256, blk, 0, stream>>>(ca);

    gemm_g1<<<dim3(32, 16), blk, 0, stream>>>(x16, 1024, win16, 1024, xz16, 4096, 1024);

    conv_silu_kernel<<<4096, blk, 0, stream>>>(xz16, conv_w, conv_b, conv_w_b, conv_b_b, xc16);

    gemm_g2<<<dim3(8, 16, 2), blk, 0, stream>>>(xc16, wx16, part);
    reduce_dbc<<<384, blk, 0, stream>>>((const float4*)part, (ushort4*)dbc16);

    gemm_g3<<<dim3(16, 16, 2), blk, 0, stream>>>(dbc16, wdt16, delta, b_dt, b_dt_b);

    scan_kernel<<<512, blk, 0, stream>>>(delta, xc16, dbc16, xz16, A_log, A_log_b, Dp, Dp_b, yf, yb);

    combine_kernel<<<4096, blk, 0, stream>>>((const uint2*)yf, (const uint2*)yb, (uint2*)yc16);

    gemm_g4<<<dim3(8, 32), blk, 0, stream>>>(yc16, 2048, wout16, 2048, out, 1024, 2048);
}